// Round 7
// baseline (84.317 us; speedup 1.0000x reference)
//
#include <hip/hip_runtime.h>

typedef __attribute__((ext_vector_type(8))) short bf16x8;
typedef __attribute__((ext_vector_type(4))) float f32x4;

constexpr int N       = 50000;
constexpr int NE      = 800000;
constexpr int AD      = 128;   // ATOM_DIM
constexpr int BD      = 16;    // BOND_DIM
constexpr int BD2     = 256;   // BD*BD
constexpr int HIDDEN  = 128;
constexpr int NBS     = 64;    // nodes per scatter block
constexpr int NBF     = 16;    // nodes per fused block (one wave); N % 16 == 0
constexpr int SSTR    = 20;    // S tile stride (floats)
constexpr int OSTR    = 132;   // out repack stride (floats)

// f32 -> bf16 round-to-nearest-even
__device__ inline short f2bf(float f) {
    union U { float f; unsigned u; } v; v.f = f;
    unsigned r = v.u + 0x7fffu + ((v.u >> 16) & 1u);
    return (short)(r >> 16);
}

// ---------------------------------------------------------------------------
// Kernel 0: build bf16 fragment-linear operand tables (kmat, Wn|Wi padded).
// ---------------------------------------------------------------------------
__global__ __launch_bounds__(256) void prep_frags(
    const float* __restrict__ kmat,
    const float* __restrict__ Wn,
    const float* __restrict__ Wi,
    short* __restrict__ kbf,
    short* __restrict__ wbf)
{
    int t = blockIdx.x * 256 + threadIdx.x;
    if (t < 4096) {
        int u = t >> 6, l = t & 63;
        int nf = u >> 2, kk = u & 3;
        int col = nf * 16 + (l & 15);
        int k0  = kk * 32 + (l >> 4) * 8;
        bf16x8 o;
#pragma unroll
        for (int j = 0; j < 8; ++j) o[j] = f2bf(kmat[(size_t)(k0 + j) * BD2 + col]);
        *(bf16x8*)(kbf + (size_t)t * 8) = o;
    } else if (t < 4096 + 1024) {
        int t2 = t - 4096;
        int u = t2 >> 6, l = t2 & 63;
        int m = u >> 3, nf2 = u & 7;
        const float* W = m ? Wi : Wn;
        int col = nf2 * 16 + (l & 15);
        int k0  = (l >> 4) * 8;
        bf16x8 o;
#pragma unroll
        for (int j = 0; j < 8; ++j) {
            int k = k0 + j;
            o[j] = (k < 16) ? f2bf(W[(size_t)k * HIDDEN + col]) : (short)0;
        }
        *(bf16x8*)(wbf + (size_t)t2 * 8) = o;
    }
}

// ---------------------------------------------------------------------------
// Kernel 1: S tiles. One block = 64 nodes. Binary search the block's edge
// range (pairs sorted by src), LDS segment-sum, coalesced tile write.
// Every S element written exactly once -> no global memset / atomics.
// ---------------------------------------------------------------------------
__global__ __launch_bounds__(256) void scatter_tile(
    const int*  __restrict__ pairs,
    const float* __restrict__ bonds,
    float* __restrict__ S)
{
    __shared__ float st[NBS * SSTR];   // 5KB

    const int tid = threadIdx.x;
    const int nb  = blockIdx.x * NBS;

    for (int i = tid; i < NBS * SSTR; i += 256) st[i] = 0.f;

    // windowed binary search (validated fallback to full range)
    int wlo = nb * 16 - 4096; if (wlo < 0) wlo = 0;
    int whi = (nb + NBS) * 16 + 4096; if (whi > NE) whi = NE;
    if (wlo > 0  && pairs[2 * wlo] >= nb)       wlo = 0;
    if (whi < NE && pairs[2 * whi] <  nb + NBS) whi = NE;
    int eLo, eHi;
    {
        int s = wlo, e = whi;
        while (s < e) { int m = (s + e) >> 1; if (pairs[2 * m] < nb) s = m + 1; else e = m; }
        eLo = s;
    }
    {
        int s = eLo, e = whi;
        while (s < e) { int m = (s + e) >> 1; if (pairs[2 * m] < nb + NBS) s = m + 1; else e = m; }
        eHi = s;
    }
    __syncthreads();   // zero done

    {
        const int g = tid >> 4;      // 16 groups of 16 lanes
        const int c = tid & 15;
        const int nE = eHi - eLo;
        const int cg = (nE + 15) >> 4;
        int gs = eLo + g * cg;
        int ge = gs + cg; if (ge > eHi) ge = eHi;
        int cur = -1; float acc = 0.f;
        int e = gs;
        for (; e + 4 <= ge; e += 4) {
            int2 pb[4]; float vb[4];
#pragma unroll
            for (int i = 0; i < 4; ++i) pb[i] = *(const int2*)(pairs + 2 * (e + i));
#pragma unroll
            for (int i = 0; i < 4; ++i) vb[i] = bonds[(size_t)pb[i].y * BD + c];
#pragma unroll
            for (int i = 0; i < 4; ++i) {
                if (pb[i].x != cur) {
                    if (cur >= 0) atomicAdd(&st[(cur - nb) * SSTR + c], acc);
                    acc = 0.f; cur = pb[i].x;
                }
                acc += vb[i];
            }
        }
        for (; e < ge; ++e) {
            int2 p = *(const int2*)(pairs + 2 * e);
            float v = bonds[(size_t)p.y * BD + c];
            if (p.x != cur) {
                if (cur >= 0) atomicAdd(&st[(cur - nb) * SSTR + c], acc);
                acc = 0.f; cur = p.x;
            }
            acc += v;
        }
        if (cur >= 0) atomicAdd(&st[(cur - nb) * SSTR + c], acc);
    }
    __syncthreads();

    // coalesced tile write: 256 threads x f32x4 = 64 nodes x 16 comps
    {
        int node = tid >> 2;
        int c4   = (tid & 3) * 4;
        if (nb + node < N) {
            f32x4 v = *(const f32x4*)(&st[node * SSTR + c4]);
            *(f32x4*)(S + (size_t)(nb + node) * BD + c4) = v;
        }
    }
}

// ---------------------------------------------------------------------------
// Kernel 2: fused per-node pipeline, ONE WAVE per 16 nodes (3125 blocks).
//  main GEMM (swapped operands) -> lane-local S contraction -> epilogue
//  MFMAs -> LDS repack -> coalesced nontemporal f32x4 stores (4 copies).
// ---------------------------------------------------------------------------
__global__ __launch_bounds__(64, 4) void fused_node16(
    const float* __restrict__ atoms,
    const float* __restrict__ bonds,
    const short* __restrict__ kbf,    // 64KB fragment-linear kmat
    const short* __restrict__ wbf,    // 16KB fragment-linear Wn|Wi
    const float* __restrict__ bias,   // 256
    const float* __restrict__ S,      // N x 16
    float* __restrict__ out)          // 4 x N x 128
{
    __shared__ float lds[NBF * OSTR];   // 8.45KB repack tile

    const int l   = threadIdx.x;   // 0..63
    const int lq  = l >> 4;
    const int lj  = l & 15;
    const int wrow = blockIdx.x * NBF;   // N % 16 == 0 -> always in range

    // ---- issue long-latency loads first -----------------------------------
    const int arow = wrow + lj;
    const float* ap = atoms + (size_t)arow * AD + lq * 8;
    float4 a0[4], a1[4];
#pragma unroll
    for (int kk = 0; kk < 4; ++kk) {
        a0[kk] = *(const float4*)(ap + kk * 32);
        a1[kk] = *(const float4*)(ap + kk * 32 + 4);
    }
    float4 sv = *(const float4*)(S + (size_t)arow * BD + lq * 4);

    // bonds fragment source (only lq<2 lanes use it)
    float4 b0 = *(const float4*)(bonds + (size_t)arow * BD + (lq & 1) * 8);
    float4 b1 = *(const float4*)(bonds + (size_t)arow * BD + (lq & 1) * 8 + 4);

    // ---- bf16 A-fragments --------------------------------------------------
    bf16x8 afrag[4];
#pragma unroll
    for (int kk = 0; kk < 4; ++kk) {
        bf16x8 af;
        af[0] = f2bf(a0[kk].x); af[1] = f2bf(a0[kk].y);
        af[2] = f2bf(a0[kk].z); af[3] = f2bf(a0[kk].w);
        af[4] = f2bf(a1[kk].x); af[5] = f2bf(a1[kk].y);
        af[6] = f2bf(a1[kk].z); af[7] = f2bf(a1[kk].w);
        afrag[kk] = af;
    }

    // ---- main GEMM, swapped operands: D[c][node] --------------------------
    f32x4 acc[16];
#pragma unroll
    for (int nf = 0; nf < 16; ++nf) acc[nf] = (f32x4){0.f, 0.f, 0.f, 0.f};

    const bf16x8* kb = (const bf16x8*)kbf;
#pragma unroll 1
    for (int kk = 0; kk < 4; ++kk) {
#pragma unroll
        for (int nf = 0; nf < 16; ++nf) {
            bf16x8 b = kb[(size_t)(nf * 4 + kk) * 64 + l];
            acc[nf] = __builtin_amdgcn_mfma_f32_16x16x32_bf16(b, afrag[kk], acc[nf], 0, 0, 0);
        }
    }

    // ---- contraction with S: every lane ends with agg[lj][0..15] ----------
    float aggf[16];
#pragma unroll
    for (int nf = 0; nf < 16; ++nf) {
        float4 bv = *(const float4*)(bias + nf * 16 + lq * 4);
        float q = (acc[nf][0] + bv.x) * sv.x
                + (acc[nf][1] + bv.y) * sv.y
                + (acc[nf][2] + bv.z) * sv.z
                + (acc[nf][3] + bv.w) * sv.w;
        q += __shfl_xor(q, 16);
        q += __shfl_xor(q, 32);
        aggf[nf] = q;
    }

    // ---- epilogue fragments (K=16 zero-padded to 32) ----------------------
    bf16x8 agg_a  = (bf16x8){0,0,0,0,0,0,0,0};
    bf16x8 bond_a = (bf16x8){0,0,0,0,0,0,0,0};
    if (lq < 2) {
#pragma unroll
        for (int j = 0; j < 8; ++j) agg_a[j] = f2bf(aggf[lq * 8 + j]);
        bond_a[0] = f2bf(b0.x); bond_a[1] = f2bf(b0.y);
        bond_a[2] = f2bf(b0.z); bond_a[3] = f2bf(b0.w);
        bond_a[4] = f2bf(b1.x); bond_a[5] = f2bf(b1.y);
        bond_a[6] = f2bf(b1.z); bond_a[7] = f2bf(b1.w);
    }

    // ---- epilogue MFMAs -> LDS repack -------------------------------------
    const bf16x8* wb = (const bf16x8*)wbf;
#pragma unroll
    for (int nf2 = 0; nf2 < 8; ++nf2) {
        bf16x8 wn_f = wb[(size_t)nf2 * 64 + l];
        bf16x8 wi_f = wb[(size_t)(8 + nf2) * 64 + l];
        f32x4 e = __builtin_amdgcn_mfma_f32_16x16x32_bf16(
            bond_a, wi_f, (f32x4){0.f, 0.f, 0.f, 0.f}, 0, 0, 0);
        e[0] = fmaxf(e[0], 0.f); e[1] = fmaxf(e[1], 0.f);
        e[2] = fmaxf(e[2], 0.f); e[3] = fmaxf(e[3], 0.f);
        f32x4 o = __builtin_amdgcn_mfma_f32_16x16x32_bf16(agg_a, wn_f, e, 0, 0, 0);
#pragma unroll
        for (int r = 0; r < 4; ++r) {
            int nl = 4 * lq + r;
            lds[nl * OSTR + nf2 * 16 + lj] = fmaxf(o[r], 0.f);
        }
    }
    __syncthreads();

    // ---- coalesced nontemporal f32x4 stores, 4 copies ---------------------
#pragma unroll
    for (int p = 0; p < 8; ++p) {
        int idx  = l + 64 * p;
        int nl   = idx >> 5;           // node within block (32 f32x4 per row)
        int h4   = (idx & 31) * 4;
        f32x4 v  = *(const f32x4*)(&lds[nl * OSTR + h4]);
        float* dst = out + (size_t)(wrow + nl) * HIDDEN + h4;
#pragma unroll
        for (int s = 0; s < 4; ++s) {
            __builtin_nontemporal_store(v, (f32x4*)(dst + (size_t)s * N * HIDDEN));
        }
    }
}

// ---------------------------------------------------------------------------
extern "C" void kernel_launch(void* const* d_in, const int* in_sizes, int n_in,
                              void* d_out, int out_size, void* d_ws, size_t ws_size,
                              hipStream_t stream)
{
    const float* atoms = (const float*)d_in[0];
    const float* bonds = (const float*)d_in[1];
    const int*   pairs = (const int*)d_in[2];
    const float* kmat  = (const float*)d_in[3];
    const float* bias  = (const float*)d_in[4];
    const float* Wn    = (const float*)d_in[5];
    const float* Wi    = (const float*)d_in[6];
    float* out = (float*)d_out;

    short* kbf = (short*)d_ws;                   // 64KB
    short* wbf = kbf + 4096 * 8;                 // 16KB
    float* S   = (float*)(wbf + 1024 * 8);       // 3.2MB

    prep_frags<<<20, 256, 0, stream>>>(kmat, Wn, Wi, kbf, wbf);
    scatter_tile<<<(N + NBS - 1) / NBS, 256, 0, stream>>>(pairs, bonds, S);
    fused_node16<<<N / NBF, 64, 0, stream>>>(
        atoms, bonds, kbf, wbf, bias, S, out);
}

// Round 9
// 76.616 us; speedup vs baseline: 1.1005x; 1.1005x over previous
//
#include <hip/hip_runtime.h>

typedef __attribute__((ext_vector_type(8))) short bf16x8;
typedef __attribute__((ext_vector_type(4))) float f32x4;

constexpr int N       = 50000;
constexpr int NE      = 800000;
constexpr int AD      = 128;   // ATOM_DIM
constexpr int BD      = 16;    // BOND_DIM
constexpr int BD2     = 256;   // BD*BD
constexpr int HIDDEN  = 128;
constexpr int NB      = 64;    // nodes per block (all node-tiled kernels)
constexpr int SSTR    = 20;    // S/agg LDS tile stride (floats)
constexpr int OSTR    = 132;   // out repack stride (floats)

// f32 -> bf16 round-to-nearest-even
__device__ inline short f2bf(float f) {
    union U { float f; unsigned u; } v; v.f = f;
    unsigned r = v.u + 0x7fffu + ((v.u >> 16) & 1u);
    return (short)(r >> 16);
}

// ---------------------------------------------------------------------------
// Kernel 0: build bf16 fragment-linear operand tables (kmat, Wn|Wi padded).
// ---------------------------------------------------------------------------
__global__ __launch_bounds__(256) void prep_frags(
    const float* __restrict__ kmat,
    const float* __restrict__ Wn,
    const float* __restrict__ Wi,
    short* __restrict__ kbf,
    short* __restrict__ wbf)
{
    int t = blockIdx.x * 256 + threadIdx.x;
    if (t < 4096) {
        int u = t >> 6, l = t & 63;
        int nf = u >> 2, kk = u & 3;
        int col = nf * 16 + (l & 15);
        int k0  = kk * 32 + (l >> 4) * 8;
        bf16x8 o;
#pragma unroll
        for (int j = 0; j < 8; ++j) o[j] = f2bf(kmat[(size_t)(k0 + j) * BD2 + col]);
        *(bf16x8*)(kbf + (size_t)t * 8) = o;
    } else if (t < 4096 + 1024) {
        int t2 = t - 4096;
        int u = t2 >> 6, l = t2 & 63;
        int m = u >> 3, nf2 = u & 7;
        const float* W = m ? Wi : Wn;
        int col = nf2 * 16 + (l & 15);
        int k0  = (l >> 4) * 8;
        bf16x8 o;
#pragma unroll
        for (int j = 0; j < 8; ++j) {
            int k = k0 + j;
            o[j] = (k < 16) ? f2bf(W[(size_t)k * HIDDEN + col]) : (short)0;
        }
        *(bf16x8*)(wbf + (size_t)t2 * 8) = o;
    }
}

// ---------------------------------------------------------------------------
// Kernel 1: S tiles. One block = 64 nodes. Binary search the block's edge
// range (pairs sorted by src), LDS segment-sum, coalesced tile write.
// ---------------------------------------------------------------------------
__global__ __launch_bounds__(256) void scatter_tile(
    const int*  __restrict__ pairs,
    const float* __restrict__ bonds,
    float* __restrict__ S)
{
    __shared__ float st[NB * SSTR];   // 5KB

    const int tid = threadIdx.x;
    const int nb  = blockIdx.x * NB;

    for (int i = tid; i < NB * SSTR; i += 256) st[i] = 0.f;

    // windowed binary search (validated fallback to full range)
    int wlo = nb * 16 - 4096; if (wlo < 0) wlo = 0;
    int whi = (nb + NB) * 16 + 4096; if (whi > NE) whi = NE;
    if (wlo > 0  && pairs[2 * wlo] >= nb)      wlo = 0;
    if (whi < NE && pairs[2 * whi] <  nb + NB) whi = NE;
    int eLo, eHi;
    {
        int s = wlo, e = whi;
        while (s < e) { int m = (s + e) >> 1; if (pairs[2 * m] < nb) s = m + 1; else e = m; }
        eLo = s;
    }
    {
        int s = eLo, e = whi;
        while (s < e) { int m = (s + e) >> 1; if (pairs[2 * m] < nb + NB) s = m + 1; else e = m; }
        eHi = s;
    }
    __syncthreads();   // zero done

    {
        const int g = tid >> 4;      // 16 groups of 16 lanes
        const int c = tid & 15;
        const int nE = eHi - eLo;
        const int cg = (nE + 15) >> 4;
        int gs = eLo + g * cg;
        int ge = gs + cg; if (ge > eHi) ge = eHi;
        int cur = -1; float acc = 0.f;
        int e = gs;
        for (; e + 4 <= ge; e += 4) {
            int2 pb[4]; float vb[4];
#pragma unroll
            for (int i = 0; i < 4; ++i) pb[i] = *(const int2*)(pairs + 2 * (e + i));
#pragma unroll
            for (int i = 0; i < 4; ++i) vb[i] = bonds[(size_t)pb[i].y * BD + c];
#pragma unroll
            for (int i = 0; i < 4; ++i) {
                if (pb[i].x != cur) {
                    if (cur >= 0) atomicAdd(&st[(cur - nb) * SSTR + c], acc);
                    acc = 0.f; cur = pb[i].x;
                }
                acc += vb[i];
            }
        }
        for (; e < ge; ++e) {
            int2 p = *(const int2*)(pairs + 2 * e);
            float v = bonds[(size_t)p.y * BD + c];
            if (p.x != cur) {
                if (cur >= 0) atomicAdd(&st[(cur - nb) * SSTR + c], acc);
                acc = 0.f; cur = p.x;
            }
            acc += v;
        }
        if (cur >= 0) atomicAdd(&st[(cur - nb) * SSTR + c], acc);
    }
    __syncthreads();

    {
        int node = tid >> 2;
        int c4   = (tid & 3) * 4;
        if (nb + node < N) {
            f32x4 v = *(const f32x4*)(&st[node * SSTR + c4]);
            *(f32x4*)(S + (size_t)(nb + node) * BD + c4) = v;
        }
    }
}

// ---------------------------------------------------------------------------
// Kernel 2: GEMM + S-contraction. 4 waves, 64 nodes/block, nf-split across
// waves (each wave reads 1/4 of kbf, 4x MFMA reuse per B fragment).
// IN-PLACE: reads S rows [nb, nb+64) and overwrites the SAME rows with agg.
// Safe: S rows are block-private, all reads complete (data dependency via
// the LDS exchange) before the barrier, writes happen after it.
// NOTE: no __restrict__ on Sagg (read+write aliased by design).
// ---------------------------------------------------------------------------
__global__ __launch_bounds__(256, 3) void gemm_contract(
    const float* __restrict__ atoms,
    const short* __restrict__ kbf,    // 64KB fragment-linear kmat
    const float* __restrict__ bias,   // 256
    float* Sagg)                      // N x 16: in = S, out = agg
{
    __shared__ float ag[NB * SSTR];   // 5KB exchange tile

    const int tid = threadIdx.x;
    const int w   = tid >> 6;
    const int l   = tid & 63;
    const int lq  = l >> 4;
    const int lj  = l & 15;
    const int nb  = blockIdx.x * NB;

    // ---- A fragments for 4 node-groups + S values -------------------------
    bf16x8 afrag[4][4];   // [ng][kk]
    float4 sval[4];
#pragma unroll
    for (int ng = 0; ng < 4; ++ng) {
        int arow = nb + ng * 16 + lj; if (arow >= N) arow = N - 1;
        const float* ap = atoms + (size_t)arow * AD + lq * 8;
#pragma unroll
        for (int kk = 0; kk < 4; ++kk) {
            float4 a0 = *(const float4*)(ap + kk * 32);
            float4 a1 = *(const float4*)(ap + kk * 32 + 4);
            bf16x8 af;
            af[0] = f2bf(a0.x); af[1] = f2bf(a0.y); af[2] = f2bf(a0.z); af[3] = f2bf(a0.w);
            af[4] = f2bf(a1.x); af[5] = f2bf(a1.y); af[6] = f2bf(a1.z); af[7] = f2bf(a1.w);
            afrag[ng][kk] = af;
        }
        sval[ng] = *(const float4*)(Sagg + (size_t)arow * BD + lq * 4);
    }

    // ---- per-nf: 16 MFMAs (4 kk x 4 ng) + lane-local contraction ----------
    const bf16x8* kb = (const bf16x8*)kbf;
    float aggf[4][4];     // [nf_local][ng]
#pragma unroll
    for (int nfl = 0; nfl < 4; ++nfl) {
        const int nf = w * 4 + nfl;
        f32x4 acc[4];
#pragma unroll
        for (int ng = 0; ng < 4; ++ng) acc[ng] = (f32x4){0.f, 0.f, 0.f, 0.f};
#pragma unroll
        for (int kk = 0; kk < 4; ++kk) {
            bf16x8 b = kb[(size_t)(nf * 4 + kk) * 64 + l];
#pragma unroll
            for (int ng = 0; ng < 4; ++ng)
                acc[ng] = __builtin_amdgcn_mfma_f32_16x16x32_bf16(b, afrag[ng][kk], acc[ng], 0, 0, 0);
        }
        float4 bv = *(const float4*)(bias + nf * 16 + lq * 4);
#pragma unroll
        for (int ng = 0; ng < 4; ++ng) {
            float q = (acc[ng][0] + bv.x) * sval[ng].x
                    + (acc[ng][1] + bv.y) * sval[ng].y
                    + (acc[ng][2] + bv.z) * sval[ng].z
                    + (acc[ng][3] + bv.w) * sval[ng].w;
            q += __shfl_xor(q, 16);
            q += __shfl_xor(q, 32);
            aggf[nfl][ng] = q;     // all 64 lanes hold the sum
        }
    }

    // ---- exchange: lane (lq,lj) writes i = w*4+lq for node ng*16+lj -------
#pragma unroll
    for (int ng = 0; ng < 4; ++ng) {
        float v = aggf[0][ng];
        v = (lq == 1) ? aggf[1][ng] : v;
        v = (lq == 2) ? aggf[2][ng] : v;
        v = (lq == 3) ? aggf[3][ng] : v;
        ag[(ng * 16 + lj) * SSTR + w * 4 + lq] = v;
    }
    __syncthreads();   // all S reads done (data dep) + exchange complete

    {
        int node = tid >> 2;
        int c4   = (tid & 3) * 4;
        if (nb + node < N) {
            f32x4 v = *(const f32x4*)(&ag[node * SSTR + c4]);
            *(f32x4*)(Sagg + (size_t)(nb + node) * BD + c4) = v;   // overwrite in place
        }
    }
}

// ---------------------------------------------------------------------------
// Kernel 3: epilogue + store streaming. Lightweight (low VGPR, high occ).
//  E = relu(bonds@Wi); out = relu(agg@Wn + E)  via 16 MFMAs per wave,
//  LDS repack -> coalesced nontemporal f32x4 stores of all 4 copies.
// ---------------------------------------------------------------------------
__global__ __launch_bounds__(256) void epilogue_store(
    const float* __restrict__ agg,    // N x 16 (the Sagg buffer)
    const float* __restrict__ bonds,  // N x 16
    const short* __restrict__ wbf,    // 16KB fragment-linear Wn|Wi
    float* __restrict__ out)          // 4 x N x 128
{
    __shared__ float lds[NB * OSTR];  // 33.8KB repack

    const int tid = threadIdx.x;
    const int w   = tid >> 6;
    const int l   = tid & 63;
    const int lq  = l >> 4;
    const int lj  = l & 15;
    const int nb  = blockIdx.x * NB;
    const int wrow = nb + w * 16;

    int arow = wrow + lj; if (arow >= N) arow = N - 1;

    bf16x8 agg_a  = (bf16x8){0,0,0,0,0,0,0,0};
    bf16x8 bond_a = (bf16x8){0,0,0,0,0,0,0,0};
    {
        int half = lq & 1;
        float4 g0 = *(const float4*)(agg   + (size_t)arow * BD + half * 8);
        float4 g1 = *(const float4*)(agg   + (size_t)arow * BD + half * 8 + 4);
        float4 b0 = *(const float4*)(bonds + (size_t)arow * BD + half * 8);
        float4 b1 = *(const float4*)(bonds + (size_t)arow * BD + half * 8 + 4);
        if (lq < 2) {
            agg_a[0] = f2bf(g0.x); agg_a[1] = f2bf(g0.y); agg_a[2] = f2bf(g0.z); agg_a[3] = f2bf(g0.w);
            agg_a[4] = f2bf(g1.x); agg_a[5] = f2bf(g1.y); agg_a[6] = f2bf(g1.z); agg_a[7] = f2bf(g1.w);
            bond_a[0] = f2bf(b0.x); bond_a[1] = f2bf(b0.y); bond_a[2] = f2bf(b0.z); bond_a[3] = f2bf(b0.w);
            bond_a[4] = f2bf(b1.x); bond_a[5] = f2bf(b1.y); bond_a[6] = f2bf(b1.z); bond_a[7] = f2bf(b1.w);
        }
    }

    const bf16x8* wb = (const bf16x8*)wbf;
#pragma unroll
    for (int nf2 = 0; nf2 < 8; ++nf2) {
        bf16x8 wn_f = wb[(size_t)nf2 * 64 + l];
        bf16x8 wi_f = wb[(size_t)(8 + nf2) * 64 + l];
        f32x4 e = __builtin_amdgcn_mfma_f32_16x16x32_bf16(
            bond_a, wi_f, (f32x4){0.f, 0.f, 0.f, 0.f}, 0, 0, 0);
        e[0] = fmaxf(e[0], 0.f); e[1] = fmaxf(e[1], 0.f);
        e[2] = fmaxf(e[2], 0.f); e[3] = fmaxf(e[3], 0.f);
        f32x4 o = __builtin_amdgcn_mfma_f32_16x16x32_bf16(agg_a, wn_f, e, 0, 0, 0);
#pragma unroll
        for (int r = 0; r < 4; ++r) {
            int nl = w * 16 + 4 * lq + r;
            lds[nl * OSTR + nf2 * 16 + lj] = fmaxf(o[r], 0.f);
        }
    }
    __syncthreads();

#pragma unroll
    for (int p = 0; p < 8; ++p) {
        int idx  = tid + 256 * p;
        int nl   = idx >> 5;
        int h4   = (idx & 31) * 4;
        int node = nb + nl;
        if (node < N) {
            f32x4 v = *(const f32x4*)(&lds[nl * OSTR + h4]);
            float* dst = out + (size_t)node * HIDDEN + h4;
#pragma unroll
            for (int s = 0; s < 4; ++s) {
                __builtin_nontemporal_store(v, (f32x4*)(dst + (size_t)s * N * HIDDEN));
            }
        }
    }
}

// ---------------------------------------------------------------------------
extern "C" void kernel_launch(void* const* d_in, const int* in_sizes, int n_in,
                              void* d_out, int out_size, void* d_ws, size_t ws_size,
                              hipStream_t stream)
{
    const float* atoms = (const float*)d_in[0];
    const float* bonds = (const float*)d_in[1];
    const int*   pairs = (const int*)d_in[2];
    const float* kmat  = (const float*)d_in[3];
    const float* bias  = (const float*)d_in[4];
    const float* Wn    = (const float*)d_in[5];
    const float* Wi    = (const float*)d_in[6];
    float* out = (float*)d_out;

    short* kbf  = (short*)d_ws;                   // 64KB
    short* wbf  = kbf + 4096 * 8;                 // 16KB
    float* Sagg = (float*)(wbf + 1024 * 8);       // 3.2MB (S, then agg in place)
    // total ws footprint: 3.28MB (matches the proven-safe rounds 1-7)

    const int nblk = (N + NB - 1) / NB;           // 782

    prep_frags<<<20, 256, 0, stream>>>(kmat, Wn, Wi, kbf, wbf);
    scatter_tile<<<nblk, 256, 0, stream>>>(pairs, bonds, Sagg);
    gemm_contract<<<nblk, 256, 0, stream>>>(atoms, kbf, bias, Sagg);
    epilogue_store<<<nblk, 256, 0, stream>>>(Sagg, bonds, wbf, out);
}